// Round 12
// baseline (257.511 us; speedup 1.0000x reference)
//
#include <hip/hip_runtime.h>
#include <math.h>
#include <utility>

typedef __attribute__((ext_vector_type(8))) short    bf16x8;
typedef __attribute__((ext_vector_type(4))) float    f32x4;
typedef __attribute__((ext_vector_type(2))) float    f32x2;
typedef __attribute__((ext_vector_type(2))) unsigned u32x2;
typedef __attribute__((ext_vector_type(4))) unsigned u32x4;

template<int I, int N, class F>
__device__ __forceinline__ void sfor(F&& f) {
    if constexpr (I < N) { f(std::integral_constant<int, I>{}); sfor<I + 1, N>(static_cast<F&&>(f)); }
}

#define NPT    50000
#define NBLK   3125     // 400000 pts / 128 per block
#define Z_S    128      // shorts per z1/z2 row (256 B), XOR-swizzled 16B columns
#define LOG2E  1.4426950408889634f

// dynamic-LDS byte offsets (all 16B-aligned)
#define OFF_Z1   0        // 128 rows (points) x 128 shorts (channels) = 32768 B
#define OFF_Z2   32768    // 32768 B
#define OFF_AOW  65536    // 4*12*8 shorts = 768 B
#define OFF_BIAS 66304    // 528 f32 = 2112 B
#define OFF_A1   68416    // 512 u32 = 2048 B
#define LDS_BYTES 70464
#define TBZ   8192   // tile-B offset in z1/z2, shorts (64 rows)

// packbf: HW v_cvt_pk_bf16_f32 (R17 win: no builtin on gfx950, inline asm
// required; the SW fallback was ~10 VALU ops and 30% of the VALU pipe).
static __device__ __forceinline__ unsigned packbf(float a, float b) {
    unsigned r;
    asm("v_cvt_pk_bf16_f32 %0, %1, %2" : "=v"(r) : "v"(a), "v"(b));
    return r;   // lo16 = bf16(a), hi16 = bf16(b)
}

#if defined(__has_builtin)
#if __has_builtin(__builtin_amdgcn_exp2f) && __has_builtin(__builtin_amdgcn_rcpf)
#define HAVE_RAW_TRANS 1
#endif
#endif

#ifdef HAVE_RAW_TRANS
static __device__ __forceinline__ float fexp2(float x) { return __builtin_amdgcn_exp2f(x); }
static __device__ __forceinline__ float frcp(float x)  { return __builtin_amdgcn_rcpf(x); }
#else
static __device__ __forceinline__ float fexp2(float x) { return __exp2f(x); }
static __device__ __forceinline__ float frcp(float x)  { return __frcp_rn(x); }
#endif

// gate2p: R7 compiler-codegen form (known-correct). ISA ledger (R8-R10):
// v_pk_add/mul_f32 assemble on gfx950; v_pk_max_f32 DOES NOT EXIST; hand
// VOP3P op_sel produced NaN — don't retry without disasm verification.
static __device__ __forceinline__ unsigned gate2p(f32x2 h, f32x2 gp) {
    f32x2 e;
    e.x = fexp2(gp.x);
    e.y = fexp2(gp.y);
    f32x2 p = e + 1.f;
    float ip = frcp(p.x * p.y);
    f32x2 ps = __builtin_shufflevector(p, p, 1, 0);
    f32x2 z = (h * ps) * ip;
    z = __builtin_elementwise_max(z, f32x2{0.f, 0.f});
    return packbf(z.x, z.y);
}

static __device__ __forceinline__ bf16x8 pack8s(const float* p, float s) { // p 16B-aligned
    f32x4 lo = *reinterpret_cast<const f32x4*>(p);
    f32x4 hi = *reinterpret_cast<const f32x4*>(p + 4);
    u32x4 u = { packbf(lo[0]*s, lo[1]*s), packbf(lo[2]*s, lo[3]*s),
                packbf(hi[0]*s, hi[1]*s), packbf(hi[2]*s, hi[3]*s) };
    return __builtin_bit_cast(bf16x8, u);
}
static __device__ __forceinline__ f32x4 mfma16(bf16x8 a, bf16x8 b, f32x4 c) {
    return __builtin_amdgcn_mfma_f32_16x16x32_bf16(a, b, c, 0, 0, 0);
}

// Round-23: FUSE L1 INTO THE OUT PHASE — each wave computes L1 for its OWN
// 16 points directly from the staging values it just computed in registers
// (B-frag = {pk(zi0,zi1),pk(zi2,tt),0,0} in q==0 lanes; A-frags iterate the
// 8 channel-groups from LDS). Deletes the zin buffer and the out->L1
// barrier: 9 barriers/block vs 13 (-30%), zin LDS round-trip gone. Write
// algebra is the w<->g transpose of the verified R13 swizzle (row = own
// point 16w+m, col-group (2g+(q>>1))^m7); L2 and out phases unchanged.
// R11 lesson: full unroll spilled (+2.7MB scratch) — back to unroll 1.
__global__ __launch_bounds__(512, 4) void node_rk4_mfma(
    const float* __restrict__ x0,
    const float* __restrict__ h1_w, const float* __restrict__ h1_b,
    const float* __restrict__ g1_w, const float* __restrict__ g1_b,
    const float* __restrict__ h2_w, const float* __restrict__ h2_b,
    const float* __restrict__ g2_w, const float* __restrict__ g2_b,
    const float* __restrict__ out_w, const float* __restrict__ out_b,
    float* __restrict__ y)
{
    extern __shared__ char lds_raw[];
    short*    z1s    = reinterpret_cast<short*>(lds_raw + OFF_Z1);
    short*    z2s    = reinterpret_cast<short*>(lds_raw + OFF_Z2);
    short*    aow_s  = reinterpret_cast<short*>(lds_raw + OFF_AOW);
    float*    bias_s = reinterpret_cast<float*>(lds_raw + OFF_BIAS);
    unsigned* a1_s   = reinterpret_cast<unsigned*>(lds_raw + OFF_A1);

    const int tid  = threadIdx.x;
    const int w    = tid >> 6;        // wave id 0..7
    const int lane = tid & 63;
    const int q    = lane >> 4;       // quad 0..3
    const int m    = lane & 15;       // MFMA row (A) / col (B,C)

    // ---------------- weight preload (once per block) ----
    const int row = 16 * w + m;                 // lane's A-row (chan) AND point id
    bf16x8 a2h[4], a2g[4];                      // layer2 A-frags per k-step (32 regs)
    sfor<0, 4>([&](auto KS) {
        constexpr int ks = KS.value;
        a2h[ks] = pack8s(h2_w + row * 128 + ks * 32 + q * 8, 1.0f);
        a2g[ks] = pack8s(g2_w + row * 128 + ks * 32 + q * 8, -LOG2E);
    });
    // layer1 A rows -> LDS compact (4 bf16 = 8 B per channel, h then g)
    if (tid < 128) {
        const f32x4 t1 = *reinterpret_cast<const f32x4*>(h1_w + tid * 4);
        const f32x4 t2 = *reinterpret_cast<const f32x4*>(g1_w + tid * 4);
        a1_s[tid * 2]           = packbf(t1[0], t1[1]);
        a1_s[tid * 2 + 1]       = packbf(t1[2], t1[3]);
        a1_s[256 + tid * 2]     = packbf(t2[0] * -LOG2E, t2[1] * -LOG2E);
        a1_s[256 + tid * 2 + 1] = packbf(t2[2] * -LOG2E, t2[3] * -LOG2E);
    }
    // out-layer A-frags -> LDS, compact: only real rows m<3 stored
    if (w == 0 && m < 3) {
        sfor<0, 4>([&](auto KS) {
            constexpr int ks = KS.value;
            bf16x8 t = pack8s(out_w + m * 128 + ks * 32 + q * 8, 2.f * LOG2E);
            *reinterpret_cast<bf16x8*>(&aow_s[((ks * 3 + m) * 4 + q) * 8]) = t;
        });
    }
    // biases -> LDS
    if (tid < 128) {
        bias_s[tid]       = h1_b[tid];
        bias_s[128 + tid] = g1_b[tid] * -LOG2E;
        bias_s[256 + tid] = h2_b[tid];
        bias_s[384 + tid] = g2_b[tid] * -LOG2E;
    }
    if (tid < 16) bias_s[512 + tid] = (tid < 3) ? out_b[tid] * (2.f * LOG2E) : 0.f;

    const float third = 1.0f / 3.0f;
    const int cb4 = 16 * w + 4 * q;   // this lane's C-frag channel base (L2)

    // swizzle helpers (verified R13): (row r, 16B-col c) lives at c ^ (r&7)
    const int m7   = m & 7;
    const int qx8  = (q ^ (m & 3)) * 8;     // q-part of swizzled col, shorts
    const int m4_8 = (m & 4) * 8;           // ks-part toggle, shorts
    const int qh   = q >> 1;
    const int ql4  = (q & 1) * 4;

    // hoisted per-lane LDS base pointers
    const short* z1_re  = &z1s[m * Z_S + qx8 + m4_8];
    const short* z1_ro  = &z1s[m * Z_S + qx8 + (m4_8 ^ 32)];
    short*       z2_wr  = &z2s[m * Z_S + (((2 * w + qh) ^ m7) * 8) + ql4];
    const short* z2_re  = &z2s[row * Z_S + qx8 + m4_8];       // own point row
    const short* z2_ro  = &z2s[row * Z_S + qx8 + (m4_8 ^ 32)];
    short*       z1f_wr = &z1s[row * Z_S + ql4];              // + swizzled group*8
    const float* bs     = &bias_s[cb4];                   // +256,+384 for L2
    const float* bsq    = &bias_s[4 * q];                 // L1 bias base (+16g,+128)
    const float* bsov   = &bias_s[512 + 4 * q];

    // ---------------- RK4 state: lanes<16 of every wave own point `row` ----
    float xc0 = 0.f, xc1 = 0.f, xc2 = 0.f;
    int gbase = 0;
    if (lane < 16) {
        const int pg = blockIdx.x * 128 + row;
        const int bb = pg / NPT;
        gbase = bb * 3 * NPT + (pg - bb * NPT);
        xc0 = x0[gbase]; xc1 = x0[gbase + NPT]; xc2 = x0[gbase + 2 * NPT];
    }
    float ax = 0.f, ay = 0.f, az = 0.f;
    float k1x = 0.f, k1y = 0.f, k1z = 0.f, k2x = 0.f, k2y = 0.f, k2z = 0.f;

    __syncthreads();   // preload visible to all waves

    // ---- hoisted stage-invariant LDS reads -> registers (R18) ----
    bf16x8 aow[4];
    {
        const short* aow_rd = &aow_s[((m < 3 ? m : 2) * 4 + q) * 8];
        sfor<0, 4>([&](auto KS) {
            constexpr int ks = KS.value;
            aow[ks] = *reinterpret_cast<const bf16x8*>(aow_rd + ks * 96);
        });
    }

    // fused L1 for this wave's own 16 points: B-frag from registers,
    // A-frags iterate 8 channel-groups from LDS. q==0 lanes carry k=0..7.
    auto L1F = [&](float zi0, float zi1, float zi2, float tt) {
        bf16x8 bin = {0, 0, 0, 0, 0, 0, 0, 0};
        if (q == 0) {
            u32x4 ub = { packbf(zi0, zi1), packbf(zi2, tt), 0u, 0u };
            bin = __builtin_bit_cast(bf16x8, ub);
        }
        sfor<0, 8>([&](auto G) {
            constexpr int g = G.value;
            bf16x8 ah = {0,0,0,0,0,0,0,0}, ag = {0,0,0,0,0,0,0,0};
            if (q == 0) {
                u32x2 th = *reinterpret_cast<const u32x2*>(&a1_s[(16 * g + m) * 2]);
                u32x2 tg = *reinterpret_cast<const u32x2*>(&a1_s[256 + (16 * g + m) * 2]);
                u32x4 uh = { th[0], th[1], 0u, 0u };
                u32x4 ug = { tg[0], tg[1], 0u, 0u };
                ah = __builtin_bit_cast(bf16x8, uh);
                ag = __builtin_bit_cast(bf16x8, ug);
            }
            const f32x4 b1h = *reinterpret_cast<const f32x4*>(bsq + 16 * g);
            const f32x4 b1g = *reinterpret_cast<const f32x4*>(bsq + 128 + 16 * g);
            f32x4 ch = mfma16(ah, bin, b1h);
            f32x4 cg = mfma16(ag, bin, b1g);
            u32x2 pk = { gate2p(f32x2{ch[0], ch[1]}, f32x2{cg[0], cg[1]}),
                         gate2p(f32x2{ch[2], ch[3]}, f32x2{cg[2], cg[3]}) };
            // col group (2g+qh) ^ m7, row = own point (row&7 == m7)
            *reinterpret_cast<u32x2*>(z1f_wr + (((2 * g + qh) ^ m7) * 8)) = pk;
        });
    };

    #pragma unroll 1
    for (int s = 0; s < 4; ++s) {
        // ---- out phase (s>0): k_s from z2 of previous stage + staging ----
        if (s > 0) {
            f32x4 vc = *reinterpret_cast<const f32x4*>(bsov);
            sfor<0, 4>([&](auto KS) {
                constexpr int ks = KS.value;
                const short* zb = (ks & 1) ? z2_ro : z2_re;
                constexpr int koff = (ks & 2) ? 64 : 0;
                bf16x8 bf = *reinterpret_cast<const bf16x8*>(zb + koff);
                vc = mfma16(aow[ks], bf, vc);
            });
            f32x2 e; e.x = fexp2(vc[0]); e.y = fexp2(vc[1]);
            f32x2 p = e + 1.f;
            const float ipxy = frcp(p.x * p.y);
            const float kx = 0.5f - p.y * ipxy;
            const float ky = 0.5f - p.x * ipxy;
            const float kz = 0.5f - frcp(fexp2(vc[2]) + 1.f);

            float zi0 = 0.f, zi1 = 0.f, zi2 = 0.f, tt = 0.f;
            if (lane < 16) {
                if (s == 1) {
                    ax = kx; ay = ky; az = kz;
                    k1x = kx; k1y = ky; k1z = kz;
                    zi0 = fmaf(kx, third, xc0);
                    zi1 = fmaf(ky, third, xc1);
                    zi2 = fmaf(kz, third, xc2); tt = third;
                } else if (s == 2) {
                    ax = fmaf(3.f, kx, ax); ay = fmaf(3.f, ky, ay); az = fmaf(3.f, kz, az);
                    k2x = kx; k2y = ky; k2z = kz;
                    zi0 = xc0 + (kx - k1x * third);
                    zi1 = xc1 + (ky - k1y * third);
                    zi2 = xc2 + (kz - k1z * third); tt = 2.f * third;
                } else {
                    ax = fmaf(3.f, kx, ax); ay = fmaf(3.f, ky, ay); az = fmaf(3.f, kz, az);
                    zi0 = xc0 + (k1x - k2x + kx);
                    zi1 = xc1 + (k1y - k2y + ky);
                    zi2 = xc2 + (k1z - k2z + kz); tt = 1.f;
                }
            }
            L1F(zi0, zi1, zi2, tt);
        } else {
            L1F(xc0, xc1, xc2, 0.f);
        }
        __syncthreads();

        // ---- layer 2 (128->128), both tiles; nt-pair split keeps acc at 16 ----
        {
            const f32x4 b2h = *reinterpret_cast<const f32x4*>(bs + 256);
            const f32x4 b2g = *reinterpret_cast<const f32x4*>(bs + 384);
            sfor<0, 2>([&](auto TT) {
                constexpr int T = TT.value;
                sfor<0, 2>([&](auto NTP) {
                    constexpr int b0 = T * TBZ + (2 * NTP.value) * 2048;
                    constexpr int b1 = T * TBZ + (2 * NTP.value + 1) * 2048;
                    f32x4 c0h, c1h, c0g, c1g;
                    {
                        bf16x8 f0 = *reinterpret_cast<const bf16x8*>(z1_re + b0);
                        bf16x8 f1 = *reinterpret_cast<const bf16x8*>(z1_re + b1);
                        c0h = mfma16(a2h[0], f0, b2h); c1h = mfma16(a2h[0], f1, b2h);
                        c0g = mfma16(a2g[0], f0, b2g); c1g = mfma16(a2g[0], f1, b2g);
                    }
                    sfor<1, 4>([&](auto KS) {
                        constexpr int ks = KS.value;
                        const short* zb = (ks & 1) ? z1_ro : z1_re;
                        constexpr int koff = (ks & 2) ? 64 : 0;
                        bf16x8 f0 = *reinterpret_cast<const bf16x8*>(zb + b0 + koff);
                        bf16x8 f1 = *reinterpret_cast<const bf16x8*>(zb + b1 + koff);
                        c0h = mfma16(a2h[ks], f0, c0h); c1h = mfma16(a2h[ks], f1, c1h);
                        c0g = mfma16(a2g[ks], f0, c0g); c1g = mfma16(a2g[ks], f1, c1g);
                    });
                    u32x2 pk0 = { gate2p(f32x2{c0h[0], c0h[1]}, f32x2{c0g[0], c0g[1]}),
                                  gate2p(f32x2{c0h[2], c0h[3]}, f32x2{c0g[2], c0g[3]}) };
                    *reinterpret_cast<u32x2*>(z2_wr + b0) = pk0;
                    u32x2 pk1 = { gate2p(f32x2{c1h[0], c1h[1]}, f32x2{c1g[0], c1g[1]}),
                                  gate2p(f32x2{c1h[2], c1h[3]}, f32x2{c1g[2], c1g[3]}) };
                    *reinterpret_cast<u32x2*>(z2_wr + b1) = pk1;
                });
            });
        }
        __syncthreads();
    }

    // ---- final out: k4 from s=3's z2, accumulate, write y ----
    {
        f32x4 vc = *reinterpret_cast<const f32x4*>(bsov);
        sfor<0, 4>([&](auto KS) {
            constexpr int ks = KS.value;
            const short* zb = (ks & 1) ? z2_ro : z2_re;
            constexpr int koff = (ks & 2) ? 64 : 0;
            bf16x8 bf = *reinterpret_cast<const bf16x8*>(zb + koff);
            vc = mfma16(aow[ks], bf, vc);
        });
        f32x2 e; e.x = fexp2(vc[0]); e.y = fexp2(vc[1]);
        f32x2 p = e + 1.f;
        const float ipxy = frcp(p.x * p.y);
        const float kx = 0.5f - p.y * ipxy;
        const float ky = 0.5f - p.x * ipxy;
        const float kz = 0.5f - frcp(fexp2(vc[2]) + 1.f);

        if (lane < 16) {
            ax += kx; ay += ky; az += kz;
            y[gbase]           = fmaf(0.125f, ax, xc0);
            y[gbase + NPT]     = fmaf(0.125f, ay, xc1);
            y[gbase + 2 * NPT] = fmaf(0.125f, az, xc2);
        }
    }
}

extern "C" void kernel_launch(void* const* d_in, const int* in_sizes, int n_in,
                              void* d_out, int out_size, void* d_ws, size_t ws_size,
                              hipStream_t stream) {
    (void)in_sizes; (void)n_in; (void)d_ws; (void)ws_size; (void)out_size;
    const float* x0    = (const float*)d_in[0];
    const float* h1_w  = (const float*)d_in[1];
    const float* h1_b  = (const float*)d_in[2];
    const float* g1_w  = (const float*)d_in[3];
    const float* g1_b  = (const float*)d_in[4];
    const float* h2_w  = (const float*)d_in[5];
    const float* h2_b  = (const float*)d_in[6];
    const float* g2_w  = (const float*)d_in[7];
    const float* g2_b  = (const float*)d_in[8];
    const float* out_w = (const float*)d_in[9];
    const float* out_b = (const float*)d_in[10];
    float* y = (float*)d_out;

    static bool attr_set = false;
    if (!attr_set) {
        (void)hipFuncSetAttribute(reinterpret_cast<const void*>(&node_rk4_mfma),
                                  hipFuncAttributeMaxDynamicSharedMemorySize, LDS_BYTES);
        attr_set = true;
    }
    node_rk4_mfma<<<NBLK, 512, LDS_BYTES, stream>>>(
        x0, h1_w, h1_b, g1_w, g1_b, h2_w, h2_b, g2_w, g2_b, out_w, out_b, y);
}

// Round 13
// 241.821 us; speedup vs baseline: 1.0649x; 1.0649x over previous
//
#include <hip/hip_runtime.h>
#include <math.h>
#include <utility>

typedef __attribute__((ext_vector_type(8))) short    bf16x8;
typedef __attribute__((ext_vector_type(4))) float    f32x4;
typedef __attribute__((ext_vector_type(2))) float    f32x2;
typedef __attribute__((ext_vector_type(2))) unsigned u32x2;
typedef __attribute__((ext_vector_type(4))) unsigned u32x4;

template<int I, int N, class F>
__device__ __forceinline__ void sfor(F&& f) {
    if constexpr (I < N) { f(std::integral_constant<int, I>{}); sfor<I + 1, N>(static_cast<F&&>(f)); }
}

#define NPT    50000
#define NBLK   3125     // 400000 pts / 128 per block (two 64-pt tiles, concurrent)
#define Z_S    128      // shorts per z1/z2 row (256 B), XOR-swizzled 16B columns
#define LOG2E  1.4426950408889634f

// dynamic-LDS byte offsets (all 16B-aligned)
#define OFF_Z1   0        // 128 rows x 128 shorts = 32768 B (tile A rows 0-63, B 64-127)
#define OFF_Z2   32768    // 32768 B
#define OFF_ZIN  65536    // 128 rows x 8 shorts = 2048 B
#define OFF_AOW  67584    // 4*12*8 shorts = 768 B
#define OFF_BIAS 68352    // 528 f32 = 2112 B
#define OFF_A1   70464    // 512 u32 = 2048 B
#define LDS_BYTES 72512
#define TBZ   8192   // tile-B offset in z1/z2, shorts (64 rows)
#define TBZIN 512    // tile-B offset in zin, shorts (64 rows)

// packbf: HW v_cvt_pk_bf16_f32 (R17 win: no builtin on gfx950, inline asm
// required; the SW fallback was ~10 VALU ops and 30% of the VALU pipe).
static __device__ __forceinline__ unsigned packbf(float a, float b) {
    unsigned r;
    asm("v_cvt_pk_bf16_f32 %0, %1, %2" : "=v"(r) : "v"(a), "v"(b));
    return r;   // lo16 = bf16(a), hi16 = bf16(b)
}

#if defined(__has_builtin)
#if __has_builtin(__builtin_amdgcn_exp2f) && __has_builtin(__builtin_amdgcn_rcpf)
#define HAVE_RAW_TRANS 1
#endif
#endif

#ifdef HAVE_RAW_TRANS
static __device__ __forceinline__ float fexp2(float x) { return __builtin_amdgcn_exp2f(x); }
static __device__ __forceinline__ float frcp(float x)  { return __builtin_amdgcn_rcpf(x); }
#else
static __device__ __forceinline__ float fexp2(float x) { return __exp2f(x); }
static __device__ __forceinline__ float frcp(float x)  { return __frcp_rn(x); }
#endif

// gate2p: R7 compiler-codegen form (known-correct, best measured).
// ISA ledger (R8-R10): v_pk_add/mul_f32 assemble on gfx950; v_pk_max_f32
// DOES NOT EXIST (pk max is f16/i16 only); hand VOP3P op_sel produced NaN
// — do not retry without disasm verification.
static __device__ __forceinline__ unsigned gate2p(f32x2 h, f32x2 gp) {
    f32x2 e;
    e.x = fexp2(gp.x);
    e.y = fexp2(gp.y);
    f32x2 p = e + 1.f;
    float ip = frcp(p.x * p.y);
    f32x2 ps = __builtin_shufflevector(p, p, 1, 0);
    f32x2 z = (h * ps) * ip;
    z = __builtin_elementwise_max(z, f32x2{0.f, 0.f});
    return packbf(z.x, z.y);
}

static __device__ __forceinline__ bf16x8 pack8s(const float* p, float s) { // p 16B-aligned
    f32x4 lo = *reinterpret_cast<const f32x4*>(p);
    f32x4 hi = *reinterpret_cast<const f32x4*>(p + 4);
    u32x4 u = { packbf(lo[0]*s, lo[1]*s), packbf(lo[2]*s, lo[3]*s),
                packbf(hi[0]*s, hi[1]*s), packbf(hi[2]*s, hi[3]*s) };
    return __builtin_bit_cast(bf16x8, u);
}
static __device__ __forceinline__ f32x4 mfma16(bf16x8 a, bf16x8 b, f32x4 c) {
    return __builtin_amdgcn_mfma_f32_16x16x32_bf16(a, b, c, 0, 0, 0);
}

// Round-25: RESTORE BEST (R7 kernel, 198.9 us) after two structural
// regressions (R11 full-unroll: spill +2.7MB scratch, 205us; R12 L1-fusion:
// per-group A-rebuild on serial path, 217us). Session ledger: occupancy
// walled at 16 waves/CU (128-reg quantum); 3 barriers/stage is the
// structural minimum (all three LDS transposes are cross-wave); only
// VALU-instruction-count cuts moved time (cvt_pk -15%); stall floor at
// 4 waves/SIMD explains VALUBusy~52 / MfmaUtil~30.
// Structure (R16+R18): uniform point id = 16w+m; all 8 waves active in
// every phase; staging fused into out-phase tail; a1/aow/k-state hoisted
// to registers; 3 barriers/stage.
__global__ __launch_bounds__(512, 4) void node_rk4_mfma(
    const float* __restrict__ x0,
    const float* __restrict__ h1_w, const float* __restrict__ h1_b,
    const float* __restrict__ g1_w, const float* __restrict__ g1_b,
    const float* __restrict__ h2_w, const float* __restrict__ h2_b,
    const float* __restrict__ g2_w, const float* __restrict__ g2_b,
    const float* __restrict__ out_w, const float* __restrict__ out_b,
    float* __restrict__ y)
{
    extern __shared__ char lds_raw[];
    short*    z1s    = reinterpret_cast<short*>(lds_raw + OFF_Z1);
    short*    z2s    = reinterpret_cast<short*>(lds_raw + OFF_Z2);
    short*    zin    = reinterpret_cast<short*>(lds_raw + OFF_ZIN);
    short*    aow_s  = reinterpret_cast<short*>(lds_raw + OFF_AOW);
    float*    bias_s = reinterpret_cast<float*>(lds_raw + OFF_BIAS);
    unsigned* a1_s   = reinterpret_cast<unsigned*>(lds_raw + OFF_A1);

    const int tid  = threadIdx.x;
    const int w    = tid >> 6;        // wave id 0..7
    const int lane = tid & 63;
    const int q    = lane >> 4;       // quad 0..3
    const int m    = lane & 15;       // MFMA row (A) / col (B,C)

    // ---------------- weight preload (once per block) ----
    const int row = 16 * w + m;                 // lane's A-row (chan) AND point id
    bf16x8 a2h[4], a2g[4];                      // layer2 A-frags per k-step (32 regs)
    sfor<0, 4>([&](auto KS) {
        constexpr int ks = KS.value;
        a2h[ks] = pack8s(h2_w + row * 128 + ks * 32 + q * 8, 1.0f);
        a2g[ks] = pack8s(g2_w + row * 128 + ks * 32 + q * 8, -LOG2E);
    });
    // layer1 A rows -> LDS compact (4 bf16 = 8 B per channel, h then g)
    if (tid < 128) {
        const f32x4 t1 = *reinterpret_cast<const f32x4*>(h1_w + tid * 4);
        const f32x4 t2 = *reinterpret_cast<const f32x4*>(g1_w + tid * 4);
        a1_s[tid * 2]           = packbf(t1[0], t1[1]);
        a1_s[tid * 2 + 1]       = packbf(t1[2], t1[3]);
        a1_s[256 + tid * 2]     = packbf(t2[0] * -LOG2E, t2[1] * -LOG2E);
        a1_s[256 + tid * 2 + 1] = packbf(t2[2] * -LOG2E, t2[3] * -LOG2E);
    }
    // out-layer A-frags -> LDS, compact: only real rows m<3 stored
    if (w == 0 && m < 3) {
        sfor<0, 4>([&](auto KS) {
            constexpr int ks = KS.value;
            bf16x8 t = pack8s(out_w + m * 128 + ks * 32 + q * 8, 2.f * LOG2E);
            *reinterpret_cast<bf16x8*>(&aow_s[((ks * 3 + m) * 4 + q) * 8]) = t;
        });
    }
    // biases -> LDS
    if (tid < 128) {
        bias_s[tid]       = h1_b[tid];
        bias_s[128 + tid] = g1_b[tid] * -LOG2E;
        bias_s[256 + tid] = h2_b[tid];
        bias_s[384 + tid] = g2_b[tid] * -LOG2E;
    }
    if (tid < 16) bias_s[512 + tid] = (tid < 3) ? out_b[tid] * (2.f * LOG2E) : 0.f;

    // zero zin (128 rows): shorts 4..7 of each row must stay 0
    if (tid < 128) *reinterpret_cast<u32x4*>(&zin[tid * 8]) = u32x4{0u, 0u, 0u, 0u};

    const float third = 1.0f / 3.0f;
    const int cb4 = 16 * w + 4 * q;   // this lane's C-frag channel base

    // swizzle helpers (verified R13): (row r, 16B-col c) lives at c ^ (r&7)
    const int m7   = m & 7;
    const int qx8  = (q ^ (m & 3)) * 8;     // q-part of swizzled col, shorts
    const int m4_8 = (m & 4) * 8;           // ks-part toggle, shorts

    // hoisted per-lane LDS base pointers (tile-A bases; tile-B = +const)
    const short* zin_rd = &zin[m * 8];
    short*       zin_wr = &zin[row * 8];                  // lanes<16, all waves
    const short* z1_re  = &z1s[m * Z_S + qx8 + m4_8];
    const short* z1_ro  = &z1s[m * Z_S + qx8 + (m4_8 ^ 32)];
    short*       z1_wr  = &z1s[m * Z_S + (((2 * w + (q >> 1)) ^ m7) * 8) + (q & 1) * 4];
    short*       z2_wr  = &z2s[m * Z_S + (((2 * w + (q >> 1)) ^ m7) * 8) + (q & 1) * 4];
    const short* z2_re  = &z2s[row * Z_S + qx8 + m4_8];       // all waves (rows 0..127)
    const short* z2_ro  = &z2s[row * Z_S + qx8 + (m4_8 ^ 32)];
    const float* bs     = &bias_s[cb4];                   // +0,+128,+256,+384
    const float* bsov   = &bias_s[512 + 4 * q];

    // ---------------- RK4 state: lanes<16 of every wave own point `row` ----
    float xc0 = 0.f, xc1 = 0.f, xc2 = 0.f;
    int gbase = 0;
    if (lane < 16) {
        const int pg = blockIdx.x * 128 + row;
        const int bb = pg / NPT;
        gbase = bb * 3 * NPT + (pg - bb * NPT);
        xc0 = x0[gbase]; xc1 = x0[gbase + NPT]; xc2 = x0[gbase + 2 * NPT];
    }
    float ax = 0.f, ay = 0.f, az = 0.f;
    float k1x = 0.f, k1y = 0.f, k1z = 0.f, k2x = 0.f, k2y = 0.f, k2z = 0.f;

    __syncthreads();   // preload visible to all waves

    // ---- hoisted stage-invariant LDS reads -> registers (R18) ----
    bf16x8 a1h = {0,0,0,0,0,0,0,0}, a1g = {0,0,0,0,0,0,0,0};
    if (q == 0) {
        u32x2 th = *reinterpret_cast<const u32x2*>(&a1_s[row * 2]);
        u32x2 tg = *reinterpret_cast<const u32x2*>(&a1_s[256 + row * 2]);
        u32x4 uh = { th[0], th[1], 0u, 0u };
        u32x4 ug = { tg[0], tg[1], 0u, 0u };
        a1h = __builtin_bit_cast(bf16x8, uh);
        a1g = __builtin_bit_cast(bf16x8, ug);
    }
    bf16x8 aow[4];
    {
        const short* aow_rd = &aow_s[((m < 3 ? m : 2) * 4 + q) * 8];
        sfor<0, 4>([&](auto KS) {
            constexpr int ks = KS.value;
            aow[ks] = *reinterpret_cast<const bf16x8*>(aow_rd + ks * 96);
        });
    }

    // prologue staging: zi = xc, tt = 0
    if (lane < 16) {
        u32x2 pk = { packbf(xc0, xc1), packbf(xc2, 0.f) };
        *reinterpret_cast<u32x2*>(zin_wr) = pk;
    }
    __syncthreads();

    #pragma unroll 1
    for (int s = 0; s < 4; ++s) {
        // ---- layer 1 (4->128), both tiles ----
        {
            const f32x4 b1h = *reinterpret_cast<const f32x4*>(bs);
            const f32x4 b1g = *reinterpret_cast<const f32x4*>(bs + 128);
            sfor<0, 2>([&](auto TT) {
                constexpr int T = TT.value;
                sfor<0, 4>([&](auto NT) {
                    constexpr int nt = NT.value;
                    bf16x8 bf = *reinterpret_cast<const bf16x8*>(zin_rd + T * TBZIN + nt * 128);
                    f32x4 ch = mfma16(a1h, bf, b1h);
                    f32x4 cg = mfma16(a1g, bf, b1g);
                    u32x2 pk = { gate2p(f32x2{ch[0], ch[1]}, f32x2{cg[0], cg[1]}),
                                 gate2p(f32x2{ch[2], ch[3]}, f32x2{cg[2], cg[3]}) };
                    *reinterpret_cast<u32x2*>(z1_wr + T * TBZ + nt * 2048) = pk;
                });
            });
        }
        __syncthreads();

        // ---- layer 2 (128->128), both tiles; nt-pair split keeps acc at 16 ----
        {
            const f32x4 b2h = *reinterpret_cast<const f32x4*>(bs + 256);
            const f32x4 b2g = *reinterpret_cast<const f32x4*>(bs + 384);
            sfor<0, 2>([&](auto TT) {
                constexpr int T = TT.value;
                sfor<0, 2>([&](auto NTP) {
                    constexpr int b0 = T * TBZ + (2 * NTP.value) * 2048;
                    constexpr int b1 = T * TBZ + (2 * NTP.value + 1) * 2048;
                    f32x4 c0h, c1h, c0g, c1g;
                    {
                        bf16x8 f0 = *reinterpret_cast<const bf16x8*>(z1_re + b0);
                        bf16x8 f1 = *reinterpret_cast<const bf16x8*>(z1_re + b1);
                        c0h = mfma16(a2h[0], f0, b2h); c1h = mfma16(a2h[0], f1, b2h);
                        c0g = mfma16(a2g[0], f0, b2g); c1g = mfma16(a2g[0], f1, b2g);
                    }
                    sfor<1, 4>([&](auto KS) {
                        constexpr int ks = KS.value;
                        const short* zb = (ks & 1) ? z1_ro : z1_re;
                        constexpr int koff = (ks & 2) ? 64 : 0;
                        bf16x8 f0 = *reinterpret_cast<const bf16x8*>(zb + b0 + koff);
                        bf16x8 f1 = *reinterpret_cast<const bf16x8*>(zb + b1 + koff);
                        c0h = mfma16(a2h[ks], f0, c0h); c1h = mfma16(a2h[ks], f1, c1h);
                        c0g = mfma16(a2g[ks], f0, c0g); c1g = mfma16(a2g[ks], f1, c1g);
                    });
                    u32x2 pk0 = { gate2p(f32x2{c0h[0], c0h[1]}, f32x2{c0g[0], c0g[1]}),
                                  gate2p(f32x2{c0h[2], c0h[3]}, f32x2{c0g[2], c0g[3]}) };
                    *reinterpret_cast<u32x2*>(z2_wr + b0) = pk0;
                    u32x2 pk1 = { gate2p(f32x2{c1h[0], c1h[1]}, f32x2{c1g[0], c1g[1]}),
                                  gate2p(f32x2{c1h[2], c1h[3]}, f32x2{c1g[2], c1g[3]}) };
                    *reinterpret_cast<u32x2*>(z2_wr + b1) = pk1;
                });
            });
        }
        __syncthreads();

        // ---- out layer (128->3) + FUSED staging; all 8 waves, own 16 pts ----
        {
            f32x4 vc = *reinterpret_cast<const f32x4*>(bsov);
            sfor<0, 4>([&](auto KS) {
                constexpr int ks = KS.value;
                const short* zb = (ks & 1) ? z2_ro : z2_re;
                constexpr int koff = (ks & 2) ? 64 : 0;
                bf16x8 bf = *reinterpret_cast<const bf16x8*>(zb + koff);
                vc = mfma16(aow[ks], bf, vc);
            });
            // khalf = tanh*0.5 = 0.5 - 1/p, p = 2^v' + 1 (scale folded into
            // out weights). Pair kx,ky through one rcp; kz single.
            f32x2 e; e.x = fexp2(vc[0]); e.y = fexp2(vc[1]);
            f32x2 p = e + 1.f;
            const float ipxy = frcp(p.x * p.y);
            const float kx = 0.5f - p.y * ipxy;
            const float ky = 0.5f - p.x * ipxy;
            const float kz = 0.5f - frcp(fexp2(vc[2]) + 1.f);

            if (lane < 16) {
                float zi0, zi1, zi2, tt;
                bool do_stage = true;
                if (s == 0) {
                    ax = kx; ay = ky; az = kz;
                    k1x = kx; k1y = ky; k1z = kz;
                    zi0 = fmaf(kx, third, xc0);
                    zi1 = fmaf(ky, third, xc1);
                    zi2 = fmaf(kz, third, xc2); tt = third;
                } else if (s == 1) {
                    ax = fmaf(3.f, kx, ax); ay = fmaf(3.f, ky, ay); az = fmaf(3.f, kz, az);
                    k2x = kx; k2y = ky; k2z = kz;
                    zi0 = xc0 + (kx - k1x * third);
                    zi1 = xc1 + (ky - k1y * third);
                    zi2 = xc2 + (kz - k1z * third); tt = 2.f * third;
                } else if (s == 2) {
                    ax = fmaf(3.f, kx, ax); ay = fmaf(3.f, ky, ay); az = fmaf(3.f, kz, az);
                    zi0 = xc0 + (k1x - k2x + kx);
                    zi1 = xc1 + (k1y - k2y + ky);
                    zi2 = xc2 + (k1z - k2z + kz); tt = 1.f;
                } else {
                    ax += kx; ay += ky; az += kz;
                    do_stage = false; zi0 = zi1 = zi2 = tt = 0.f;
                }
                if (do_stage) {
                    u32x2 pk = { packbf(zi0, zi1), packbf(zi2, tt) };
                    *reinterpret_cast<u32x2*>(zin_wr) = pk;
                }
            }
        }
        if (s < 3) __syncthreads();
    }

    if (lane < 16) {
        y[gbase]           = fmaf(0.125f, ax, xc0);
        y[gbase + NPT]     = fmaf(0.125f, ay, xc1);
        y[gbase + 2 * NPT] = fmaf(0.125f, az, xc2);
    }
}

extern "C" void kernel_launch(void* const* d_in, const int* in_sizes, int n_in,
                              void* d_out, int out_size, void* d_ws, size_t ws_size,
                              hipStream_t stream) {
    (void)in_sizes; (void)n_in; (void)d_ws; (void)ws_size; (void)out_size;
    const float* x0    = (const float*)d_in[0];
    const float* h1_w  = (const float*)d_in[1];
    const float* h1_b  = (const float*)d_in[2];
    const float* g1_w  = (const float*)d_in[3];
    const float* g1_b  = (const float*)d_in[4];
    const float* h2_w  = (const float*)d_in[5];
    const float* h2_b  = (const float*)d_in[6];
    const float* g2_w  = (const float*)d_in[7];
    const float* g2_b  = (const float*)d_in[8];
    const float* out_w = (const float*)d_in[9];
    const float* out_b = (const float*)d_in[10];
    float* y = (float*)d_out;

    static bool attr_set = false;
    if (!attr_set) {
        (void)hipFuncSetAttribute(reinterpret_cast<const void*>(&node_rk4_mfma),
                                  hipFuncAttributeMaxDynamicSharedMemorySize, LDS_BYTES);
        attr_set = true;
    }
    node_rk4_mfma<<<NBLK, 512, LDS_BYTES, stream>>>(
        x0, h1_w, h1_b, g1_w, g1_b, h2_w, h2_b, g2_w, g2_b, out_w, out_b, y);
}